// Round 1
// baseline (412.407 us; speedup 1.0000x reference)
//
#include <hip/hip_runtime.h>
#include <hip/hip_bf16.h>
#include <math.h>

// Top-p (nucleus) + exponential-minimum sampling, one block per row.
// Key identities:
//   - sort by prob desc == sort by logit desc (softmax monotone)
//   - kept set == { l >= lambda* } where lambda* is where descending
//     cumulative exp-mass crosses TOP_P * total_mass (fp64 accumulation)
//   - argmin -log(xi)/p == argmin [ log(-log(xi)) - l ]  (monotone transform)
// So: histogram exp(l) into 4096 logit bins -> find boundary bin ->
// gather ~200 boundary-bin tokens, sort, sequential fp64 accumulate to find
// lambda* -> block-wide argmin over kept -> fill output.

constexpr int   NBINS   = 4096;
constexpr int   CAP     = 2048;      // boundary-bin gather capacity (~200 expected)
constexpr float BIN_MIN = -8.0f;
constexpr float BIN_SCALE = 256.0f;  // bins per unit logit; range [-8, 8)
constexpr float NEG_FILL = -100000.0f;
constexpr float POS_FILL =  100000.0f;
constexpr float TOPP     = 0.9f;

__global__ __launch_bounds__(1024)
void topp_expmin_kernel(const float* __restrict__ logits,
                        const float* __restrict__ xi,
                        float* __restrict__ out,
                        int V)
{
    const int row = blockIdx.x;
    const int tid = threadIdx.x;
    const float* rowp = logits + (size_t)row * V;
    float*       outp = out    + (size_t)row * V;
    const int NV4 = V >> 2;

    __shared__ float  hist[NBINS];
    __shared__ float  gl_l[CAP];
    __shared__ float  gl_x[CAP];
    __shared__ int    gl_i[CAP];
    __shared__ int    gl_count;
    __shared__ int    sBinB;
    __shared__ double sCumAbove;
    __shared__ double sTarget;
    __shared__ int    sKeptN;
    __shared__ float  rkey[16];
    __shared__ int    ridx[16];
    __shared__ int    sWinner;

    // ---- init LDS ----
    for (int i = tid; i < NBINS; i += 1024) hist[i] = 0.0f;
    if (tid == 0) gl_count = 0;
    __syncthreads();

    // ---- pass 1: histogram of exp(l) over logit bins (f32 LDS atomics) ----
    const float4* row4 = reinterpret_cast<const float4*>(rowp);
    for (int j = tid; j < NV4; j += 1024) {
        float4 L = row4[j];
        float lv[4] = {L.x, L.y, L.z, L.w};
        #pragma unroll
        for (int c = 0; c < 4; ++c) {
            float l = lv[c];
            float e = expf(l);
            int b = (int)floorf((l - BIN_MIN) * BIN_SCALE);
            b = min(max(b, 0), NBINS - 1);
            atomicAdd(&hist[b], e);
        }
    }
    __syncthreads();

    // ---- wave-0 descending scan over bins: find boundary bin B ----
    if (tid < 64) {
        const int lane = tid;
        const int hi = NBINS - 1 - (lane << 6);   // top bin of this lane's chunk
        double seg = 0.0;
        for (int k = 0; k < 64; ++k) seg += (double)hist[hi - k];
        // inclusive prefix over lanes (lane 0 = topmost chunk)
        double v = seg;
        for (int off = 1; off < 64; off <<= 1) {
            double u = __shfl_up(v, off);
            if (lane >= off) v += u;
        }
        double excl   = v - seg;
        double total  = __shfl(v, 63);
        double target = (double)TOPP * total;
        // walk own chunk high->low; first bin where cum+h >= target
        int    candBin = -1;
        double candS   = 0.0;
        double cum = excl;
        for (int k = 0; k < 64; ++k) {
            int b = hi - k;
            double h = (double)hist[b];
            if (candBin < 0 && cum + h >= target) { candBin = b; candS = cum; }
            cum += h;
        }
        // max-bin reduce across lanes (crossing bin is the max candidate)
        for (int off = 32; off >= 1; off >>= 1) {
            int    ob = __shfl_xor(candBin, off);
            double os = __shfl_xor(candS, off);
            if (ob > candBin) { candBin = ob; candS = os; }
        }
        if (lane == 0) { sBinB = candBin; sCumAbove = candS; sTarget = target; }
    }
    __syncthreads();

    const int binB = sBinB;

    // ---- pass 2: argmin over bins>B; gather bin-B tokens ----
    float bestKey = INFINITY;
    int   bestIdx = 0x7fffffff;
    const float4* xi4 = reinterpret_cast<const float4*>(xi);
    for (int j = tid; j < NV4; j += 1024) {
        float4 L = row4[j];
        float4 X = xi4[j];
        float lv[4] = {L.x, L.y, L.z, L.w};
        float xv[4] = {X.x, X.y, X.z, X.w};
        #pragma unroll
        for (int c = 0; c < 4; ++c) {
            float l = lv[c];
            int b = (int)floorf((l - BIN_MIN) * BIN_SCALE);
            b = min(max(b, 0), NBINS - 1);
            if (b > binB) {
                float key = logf(-logf(xv[c])) - l;
                int idx = (j << 2) + c;
                if (key < bestKey || (key == bestKey && idx < bestIdx)) {
                    bestKey = key; bestIdx = idx;
                }
            } else if (b == binB) {
                int p = atomicAdd(&gl_count, 1);
                if (p < CAP) { gl_l[p] = l; gl_x[p] = xv[c]; gl_i[p] = (j << 2) + c; }
            }
        }
    }
    __syncthreads();

    // ---- bitonic sort boundary list descending by l ----
    int n = gl_count; if (n > CAP) n = CAP;
    int P = 1; while (P < n) P <<= 1;
    if (P < 2) P = 2;
    for (int i = tid; i < P; i += 1024) {
        if (i >= n) { gl_l[i] = -INFINITY; gl_x[i] = 0.5f; gl_i[i] = 0x7fffffff; }
    }
    for (int size = 2; size <= P; size <<= 1) {
        for (int stride = size >> 1; stride > 0; stride >>= 1) {
            __syncthreads();
            for (int i = tid; i < P; i += 1024) {
                int j = i ^ stride;
                if (j > i) {
                    bool up = ((i & size) == 0);     // descending overall
                    float li = gl_l[i], lj = gl_l[j];
                    bool sw = up ? (li < lj) : (li > lj);
                    if (sw) {
                        gl_l[i] = lj; gl_l[j] = li;
                        float tx = gl_x[i]; gl_x[i] = gl_x[j]; gl_x[j] = tx;
                        int   ti = gl_i[i]; gl_i[i] = gl_i[j]; gl_i[j] = ti;
                    }
                }
            }
        }
    }
    __syncthreads();

    // ---- sequential fp64 accumulation within boundary bin -> kept count ----
    if (tid == 0) {
        double cum = sCumAbove;
        double target = sTarget;
        int kept = n;                   // default: whole bin kept
        for (int k = 0; k < n; ++k) {
            cum += (double)expf(gl_l[k]);
            if (cum >= target) { kept = k + 1; break; }   // crossing token included
        }
        sKeptN = kept;
    }
    __syncthreads();

    // ---- merge kept boundary-bin tokens into argmin ----
    const int keptN = sKeptN;
    for (int k = tid; k < keptN; k += 1024) {
        float key = logf(-logf(gl_x[k])) - gl_l[k];
        int idx = gl_i[k];
        if (key < bestKey || (key == bestKey && idx < bestIdx)) {
            bestKey = key; bestIdx = idx;
        }
    }
    // block argmin reduce: wave shuffle then cross-wave via LDS
    for (int off = 32; off >= 1; off >>= 1) {
        float ok = __shfl_down(bestKey, off);
        int   oi = __shfl_down(bestIdx, off);
        if (ok < bestKey || (ok == bestKey && oi < bestIdx)) { bestKey = ok; bestIdx = oi; }
    }
    const int wave = tid >> 6;
    if ((tid & 63) == 0) { rkey[wave] = bestKey; ridx[wave] = bestIdx; }
    __syncthreads();
    if (tid == 0) {
        float bk = rkey[0]; int bi = ridx[0];
        for (int w = 1; w < 16; ++w) {
            if (rkey[w] < bk || (rkey[w] == bk && ridx[w] < bi)) { bk = rkey[w]; bi = ridx[w]; }
        }
        sWinner = bi;
    }
    __syncthreads();
    const int win = sWinner;

    // ---- fill output row ----
    float4* out4 = reinterpret_cast<float4*>(outp);
    const int winj = win >> 2;
    for (int j = tid; j < NV4; j += 1024) {
        float4 o = make_float4(NEG_FILL, NEG_FILL, NEG_FILL, NEG_FILL);
        if (j == winj) {
            float ov[4] = {o.x, o.y, o.z, o.w};
            ov[win & 3] = POS_FILL;
            o = make_float4(ov[0], ov[1], ov[2], ov[3]);
        }
        out4[j] = o;
    }
}

extern "C" void kernel_launch(void* const* d_in, const int* in_sizes, int n_in,
                              void* d_out, int out_size, void* d_ws, size_t ws_size,
                              hipStream_t stream) {
    // d_in[0] = input_ids (int64, unused by the computation)
    // d_in[1] = logits f32 [B, V]
    // d_in[2] = xi     f32 [V]
    const float* logits = (const float*)d_in[1];
    const float* xi     = (const float*)d_in[2];
    float*       out    = (float*)d_out;
    const int V = in_sizes[2];
    const int B = in_sizes[1] / V;
    topp_expmin_kernel<<<B, 1024, 0, stream>>>(logits, xi, out, V);
}